// Round 2
// baseline (721.314 us; speedup 1.0000x reference)
//
#include <hip/hip_runtime.h>

typedef __bf16 bf16;
typedef __bf16 bf16x8 __attribute__((ext_vector_type(8)));
typedef __bf16 bf16x4 __attribute__((ext_vector_type(4)));
typedef float  f32x4  __attribute__((ext_vector_type(4)));

#define SCALE 0.125f   // Dh^-0.5, exact in bf16

__device__ __forceinline__ void gl_lds16(const bf16* g, bf16* l) {
  __builtin_amdgcn_global_load_lds(
      (const __attribute__((address_space(1))) void*)g,
      (__attribute__((address_space(3))) void*)l, 16, 0, 0);
}

// ---------------------------------------------------------------- casts/prep
__global__ __launch_bounds__(256) void cast4_kernel(const float* __restrict__ src,
                                                    bf16* __restrict__ dst, int n4) {
  int i = blockIdx.x * 256 + threadIdx.x;
  if (i >= n4) return;
  float4 v = ((const float4*)src)[i];
  bf16x4 o = { (bf16)v.x, (bf16)v.y, (bf16)v.z, (bf16)v.w };
  *(bf16x4*)(dst + (size_t)i * 4) = o;
}

// Builds Wqkvt (2304x768) = [Wq|Wkv]^T in bf16, Wpt (768x768) = Wp^T, bias1 = bq|bkv
__global__ __launch_bounds__(256) void prep_weights(
    const float* __restrict__ Wq, const float* __restrict__ Wkv,
    const float* __restrict__ Wp, const float* __restrict__ bq,
    const float* __restrict__ bkv,
    bf16* __restrict__ Wqkvt, bf16* __restrict__ Wpt, float* __restrict__ bias1) {
  int idx = blockIdx.x * 256 + threadIdx.x;
  const int T1 = 2304 * 768, T2 = 768 * 768;
  if (idx < T1) {
    int c = idx / 768, j = idx - c * 768;
    float v = (c < 768) ? Wq[(size_t)j * 768 + c] : Wkv[(size_t)j * 1536 + (c - 768)];
    Wqkvt[idx] = (bf16)v;
  } else if (idx < T1 + T2) {
    int t2 = idx - T1;
    int c = t2 / 768, j = t2 - c * 768;
    Wpt[t2] = (bf16)Wp[(size_t)j * 768 + c];
  } else if (idx < T1 + T2 + 2304) {
    int c = idx - T1 - T2;
    bias1[c] = (c < 768) ? bq[c] : bkv[c - 768];
  }
}

// ---------------------------------------------------------------- GEMM (A MxK, Bt NxK, bf16, fp32 acc)
// 128x128 tile, 4 waves in 2x2, each wave 64x64 = 4x4 mfma_f32_16x16x32_bf16 tiles.
__global__ __launch_bounds__(256) void gemm_bt(
    const bf16* __restrict__ A, const bf16* __restrict__ Bt,
    const float* __restrict__ bias,
    bf16* __restrict__ Cb, float* __restrict__ Cf,
    int Mdim, int Ndim, int Kdim) {
  __shared__ alignas(16) bf16 As[128 * 32];
  __shared__ alignas(16) bf16 Bs[128 * 32];
  int tid = threadIdx.x;
  int lane = tid & 63, wave = tid >> 6;
  int wr = wave >> 1, wc = wave & 1;
  int bm = blockIdx.y * 128, bn = blockIdx.x * 128;
  int lr = lane & 15, quad = lane >> 4;
  f32x4 acc[4][4] = {};
  for (int kb = 0; kb < Kdim; kb += 32) {
    __syncthreads();
#pragma unroll
    for (int i = 0; i < 2; i++) {
      int c = tid + i * 256;          // 512 16B-chunks per tile; LDS byte = c*16
      int r = c >> 2, cc = (c & 3) * 8;
      bf16* ldsbase_a = As + ((size_t)i * 256 + wave * 64) * 8;  // wave-uniform
      bf16* ldsbase_b = Bs + ((size_t)i * 256 + wave * 64) * 8;
      gl_lds16(A + (size_t)(bm + r) * Kdim + kb + cc, ldsbase_a);
      gl_lds16(Bt + (size_t)(bn + r) * Kdim + kb + cc, ldsbase_b);
    }
    __syncthreads();
    bf16x8 af[4], bg[4];
#pragma unroll
    for (int mi = 0; mi < 4; mi++)
      af[mi] = *(const bf16x8*)(As + (wr * 64 + mi * 16 + lr) * 32 + quad * 8);
#pragma unroll
    for (int ni = 0; ni < 4; ni++)
      bg[ni] = *(const bf16x8*)(Bs + (wc * 64 + ni * 16 + lr) * 32 + quad * 8);
#pragma unroll
    for (int mi = 0; mi < 4; mi++)
#pragma unroll
      for (int ni = 0; ni < 4; ni++)
        acc[mi][ni] = __builtin_amdgcn_mfma_f32_16x16x32_bf16(af[mi], bg[ni], acc[mi][ni], 0, 0, 0);
  }
#pragma unroll
  for (int mi = 0; mi < 4; mi++)
#pragma unroll
    for (int ni = 0; ni < 4; ni++)
#pragma unroll
      for (int r = 0; r < 4; r++) {
        int row = bm + wr * 64 + mi * 16 + quad * 4 + r;
        int col = bn + wc * 64 + ni * 16 + lr;
        float v = acc[mi][ni][r] + bias[col];
        if (Cb) Cb[(size_t)row * Ndim + col] = (bf16)v;
        else    Cf[(size_t)row * Ndim + col] = v;
      }
}

// ---------------------------------------------------------------- generalized thin GEMM
// 128(M) x 64(N) tile, 4 waves 2x2 (each 64x32). Strided A/B/C with per-z offsets
// for batched-per-head use. Optional epilogue: C += bias[z*biasZ+col] * rowscale[row*rsLd+z].
__global__ __launch_bounds__(256) void gemm_bt_g(
    const bf16* __restrict__ A, int lda, int aZ,
    const bf16* __restrict__ Bt, int ldb, int bZ,
    bf16* __restrict__ Cb, float* __restrict__ Cf, int ldc, int cZ,
    const float* __restrict__ bias, int biasZ,
    const float* __restrict__ rowscale, int rsLd,
    int Kdim) {
  __shared__ alignas(16) bf16 As[128 * 32];
  __shared__ alignas(16) bf16 Bs[64 * 32];
  int tid = threadIdx.x;
  int lane = tid & 63, wave = tid >> 6;
  int wr = wave >> 1, wc = wave & 1;
  int bm = blockIdx.y * 128, bn = blockIdx.x * 64;
  int z = blockIdx.z;
  const bf16* Ab = A + (size_t)z * aZ;
  const bf16* Bb = Bt + (size_t)z * bZ;
  int lr = lane & 15, quad = lane >> 4;
  f32x4 acc[4][2] = {};
  for (int kb = 0; kb < Kdim; kb += 32) {
    __syncthreads();
#pragma unroll
    for (int i = 0; i < 2; i++) {
      int c = tid + i * 256;
      int r = c >> 2, cc = (c & 3) * 8;
      gl_lds16(Ab + (size_t)(bm + r) * lda + kb + cc,
               As + ((size_t)i * 256 + wave * 64) * 8);
    }
    {
      int r = tid >> 2, cc = (tid & 3) * 8;
      gl_lds16(Bb + (size_t)(bn + r) * ldb + kb + cc,
               Bs + (size_t)(wave * 64) * 8);
    }
    __syncthreads();
    bf16x8 af[4], bg[2];
#pragma unroll
    for (int mi = 0; mi < 4; mi++)
      af[mi] = *(const bf16x8*)(As + (wr * 64 + mi * 16 + lr) * 32 + quad * 8);
#pragma unroll
    for (int ni = 0; ni < 2; ni++)
      bg[ni] = *(const bf16x8*)(Bs + (wc * 32 + ni * 16 + lr) * 32 + quad * 8);
#pragma unroll
    for (int mi = 0; mi < 4; mi++)
#pragma unroll
      for (int ni = 0; ni < 2; ni++)
        acc[mi][ni] = __builtin_amdgcn_mfma_f32_16x16x32_bf16(af[mi], bg[ni], acc[mi][ni], 0, 0, 0);
  }
#pragma unroll
  for (int mi = 0; mi < 4; mi++)
#pragma unroll
    for (int ni = 0; ni < 2; ni++)
#pragma unroll
      for (int r = 0; r < 4; r++) {
        int row = bm + wr * 64 + mi * 16 + quad * 4 + r;
        int col = wc * 32 + ni * 16 + lr;
        float v = acc[mi][ni][r];
        if (bias) {
          float sc = rowscale ? rowscale[(size_t)row * rsLd + z] : 1.f;
          v += bias[z * biasZ + col] * sc;
        }
        size_t idx = (size_t)row * ldc + (size_t)z * cZ + bn + col;
        if (Cb) Cb[idx] = (bf16)v;
        else    Cf[idx] = v;
      }
}

// ---------------------------------------------------------------- sim logits + softmax + weighted-sim
// One block per (b,n) pair. Reads fp32 sim directly (no cast pass) and U[bn,h,:]=Wk_h q_h;
// logits[h,m] = sim_m . U_h (+ q_h.bk_h); softmax over m -> msim,lsim; then overwrites U
// in place with S~[h,:] = sum_m w[h,m] sim_m (feeds O-GEMM: osim = S~ @ Wv + lsim*bv).
__global__ __launch_bounds__(256) void sim_logits(
    const float* __restrict__ sim,      // chunk base: [CH][8][768] fp32
    bf16* __restrict__ U,               // chunk base: [CH][12][768] bf16 (read, then S~ written)
    const bf16* __restrict__ qkv,
    const float* __restrict__ bias1,
    int bn0,
    float* __restrict__ msim, float* __restrict__ lsim) {
  __shared__ alignas(16) float simS[8][772];   // +4 pad: m-stride -> 4 banks
  __shared__ alignas(16) bf16  uS[12][776];    // +8 pad: h-stride -> 4 banks
  __shared__ float logitS[12][8];
  __shared__ float wS[12][8];
  __shared__ float cS[12];
  int t = threadIdx.x;
  int pair = blockIdx.x;
  int bn = bn0 + pair;
  // load sim fp32 (8x768 = 1536 float4)
  const float4* s4 = (const float4*)(sim + (size_t)pair * 6144);
#pragma unroll
  for (int ii = 0; ii < 6; ii++) {
    int i = t + ii * 256;
    float4 v = s4[i];
    int m = i / 192, jj = (i - m * 192) * 4;
    *(float4*)(&simS[m][jj]) = v;
  }
  // load U bf16 (12x768 = 1152 int4)
  const int4* u4 = (const int4*)(U + (size_t)pair * 9216);
  for (int i = t; i < 1152; i += 256) {
    int h = i / 96, c8 = (i - h * 96) * 8;
    *(int4*)(&uS[h][c8]) = u4[i];
  }
  // bias constant c_h = q_h . bk_h (zero when bkv==0, kept for generality)
  if (t < 96) {
    int h = t >> 3, d0 = (t & 7) * 8;
    bf16 qq[8];
    *(int4*)qq = *(const int4*)(qkv + (size_t)bn * 2304 + h * 64 + d0);
    float s = 0.f;
#pragma unroll
    for (int e = 0; e < 8; e++) s += (float)qq[e] * bias1[768 + h * 64 + d0 + e];
    s += __shfl_xor(s, 1, 64);
    s += __shfl_xor(s, 2, 64);
    s += __shfl_xor(s, 4, 64);
    if ((t & 7) == 0) cS[h] = s;
  }
  __syncthreads();
  // logits: 96 dots of length 768, 2 threads/dot on interleaved 8-elem chunks
  if (t < 192) {
    int hm = t >> 1, half = t & 1;
    int h = hm >> 3, m = hm & 7;
    float s = 0.f;
#pragma unroll 8
    for (int kk = 0; kk < 48; kk++) {
      int j0 = kk * 16 + half * 8;
      bf16x8 uv = *(const bf16x8*)(&uS[h][j0]);
      float4 a = *(const float4*)(&simS[m][j0]);
      float4 b = *(const float4*)(&simS[m][j0 + 4]);
      s += a.x * (float)uv[0] + a.y * (float)uv[1] + a.z * (float)uv[2] + a.w * (float)uv[3]
         + b.x * (float)uv[4] + b.y * (float)uv[5] + b.z * (float)uv[6] + b.w * (float)uv[7];
    }
    s += __shfl_xor(s, 1, 64);
    if (!half) logitS[h][m] = (s + cS[h]) * SCALE;
  }
  __syncthreads();
  if (t < 12) {
    float mx = logitS[t][0];
#pragma unroll
    for (int m = 1; m < 8; m++) mx = fmaxf(mx, logitS[t][m]);
    float l = 0.f;
#pragma unroll
    for (int m = 0; m < 8; m++) { float e = __expf(logitS[t][m] - mx); wS[t][m] = e; l += e; }
    msim[(size_t)bn * 12 + t] = mx;
    lsim[(size_t)bn * 12 + t] = l;
  }
  __syncthreads();
  // S~[h][j] = sum_m w[h][m] * sim[m][j]  -> overwrite U (paired bf16 stores)
  bf16* Sw = U + (size_t)pair * 9216;
  for (int i = t; i < 4608; i += 256) {
    int h = i / 384, j2 = (i - h * 384) * 2;
    float s0 = 0.f, s1 = 0.f;
#pragma unroll
    for (int m = 0; m < 8; m++) {
      float w = wS[h][m];
      s0 += w * simS[m][j2];
      s1 += w * simS[m][j2 + 1];
    }
    bf16 pr[2] = { (bf16)s0, (bf16)s1 };
    *(unsigned*)(&Sw[(size_t)h * 768 + j2]) = *(unsigned*)pr;
  }
}

// ---------------------------------------------------------------- self attention + merge (flash-style)
__global__ __launch_bounds__(256) void self_attn(
    const bf16* __restrict__ qkv,
    const float* __restrict__ msim, const float* __restrict__ lsim,
    const float* __restrict__ osim,
    bf16* __restrict__ attn_out) {
  __shared__ alignas(16) bf16 Ks[128][72];     // K tile rows (j,d)
  __shared__ alignas(16) bf16 Vt[64][136];     // V^T tile (d, j)
  __shared__ alignas(16) bf16 Ps[4][16][136];  // per-wave P strip (qrow, j)
  int bid = blockIdx.x;
  int qc = bid & 7;
  int h  = (bid >> 3) % 12;
  int b  = bid / 96;
  int rowbase = b * 512;
  int q0 = qc * 64;
  int t = threadIdx.x, lane = t & 63, wv = t >> 6;
  int lr = lane & 15, quad = lane >> 4;

  const bf16* qrow = qkv + (size_t)(rowbase + q0 + wv * 16 + lr) * 2304 + h * 64;
  bf16x8 aq0 = *(const bf16x8*)(qrow + quad * 8);
  bf16x8 aq1 = *(const bf16x8*)(qrow + 32 + quad * 8);

  f32x4 oacc[4] = {};
  float mrow[4], lrow[4];
#pragma unroll
  for (int r = 0; r < 4; r++) { mrow[r] = -1e30f; lrow[r] = 0.f; }

  for (int kt = 0; kt < 4; kt++) {
    int jb = kt * 128;
    __syncthreads();
    for (int ci = t; ci < 1024; ci += 256) {
      int j = ci >> 3, off = (ci & 7) * 8;
      *(int4*)(&Ks[j][off]) =
          *(const int4*)(qkv + (size_t)(rowbase + jb + j) * 2304 + 768 + h * 64 + off);
    }
    for (int ci = t; ci < 512; ci += 256) {
      int jp = ci >> 3, off = (ci & 7) * 8;
      const bf16* v0 = qkv + (size_t)(rowbase + jb + jp * 2) * 2304 + 1536 + h * 64 + off;
      bf16 ta[8], tb[8];
      *(int4*)ta = *(const int4*)v0;
      *(int4*)tb = *(const int4*)(v0 + 2304);
#pragma unroll
      for (int e = 0; e < 8; e++) {
        bf16 pr[2] = { ta[e], tb[e] };
        *(unsigned*)(&Vt[off + e][jp * 2]) = *(unsigned*)pr;
      }
    }
    __syncthreads();

    f32x4 sacc[8] = {};
#pragma unroll
    for (int ni = 0; ni < 8; ni++) {
      int jj = ni * 16 + lr;
      bf16x8 bk0 = *(const bf16x8*)(&Ks[jj][quad * 8]);
      bf16x8 bk1 = *(const bf16x8*)(&Ks[jj][32 + quad * 8]);
      sacc[ni] = __builtin_amdgcn_mfma_f32_16x16x32_bf16(aq0, bk0, sacc[ni], 0, 0, 0);
      sacc[ni] = __builtin_amdgcn_mfma_f32_16x16x32_bf16(aq1, bk1, sacc[ni], 0, 0, 0);
    }
    float tm[4];
#pragma unroll
    for (int r = 0; r < 4; r++) {
      float v = sacc[0][r];
#pragma unroll
      for (int ni = 1; ni < 8; ni++) v = fmaxf(v, sacc[ni][r]);
      tm[r] = v;
    }
#pragma unroll
    for (int s = 1; s < 16; s <<= 1)
#pragma unroll
      for (int r = 0; r < 4; r++) tm[r] = fmaxf(tm[r], __shfl_xor(tm[r], s, 64));
    float alpha[4], s4[4];
#pragma unroll
    for (int r = 0; r < 4; r++) {
      float mnew = fmaxf(mrow[r], tm[r] * SCALE);
      alpha[r] = __expf(mrow[r] - mnew);
      mrow[r] = mnew;
      s4[r] = 0.f;
    }
#pragma unroll
    for (int ni = 0; ni < 8; ni++)
#pragma unroll
      for (int r = 0; r < 4; r++) {
        float p = __expf(sacc[ni][r] * SCALE - mrow[r]);
        s4[r] += p;
        Ps[wv][quad * 4 + r][ni * 16 + lr] = (bf16)p;
      }
#pragma unroll
    for (int s = 1; s < 16; s <<= 1)
#pragma unroll
      for (int r = 0; r < 4; r++) s4[r] += __shfl_xor(s4[r], s, 64);
#pragma unroll
    for (int r = 0; r < 4; r++) lrow[r] = lrow[r] * alpha[r] + s4[r];
#pragma unroll
    for (int ni = 0; ni < 4; ni++)
#pragma unroll
      for (int r = 0; r < 4; r++) oacc[ni][r] *= alpha[r];

#pragma unroll
    for (int kb = 0; kb < 4; kb++) {
      bf16x8 ap = *(const bf16x8*)(&Ps[wv][lr][kb * 32 + quad * 8]);
#pragma unroll
      for (int ni = 0; ni < 4; ni++) {
        bf16x8 bv = *(const bf16x8*)(&Vt[ni * 16 + lr][kb * 32 + quad * 8]);
        oacc[ni] = __builtin_amdgcn_mfma_f32_16x16x32_bf16(ap, bv, oacc[ni], 0, 0, 0);
      }
    }
  }

#pragma unroll
  for (int r = 0; r < 4; r++) {
    int bnI = rowbase + q0 + wv * 16 + quad * 4 + r;
    float ms = msim[(size_t)bnI * 12 + h], ls = lsim[(size_t)bnI * 12 + h];
    float mt = fmaxf(mrow[r], ms);
    float ea = __expf(mrow[r] - mt), eb = __expf(ms - mt);
    float inv = 1.f / (lrow[r] * ea + ls * eb);
#pragma unroll
    for (int ni = 0; ni < 4; ni++) {
      int d = ni * 16 + lr;
      float val = (oacc[ni][r] * ea + osim[(size_t)bnI * 768 + h * 64 + d] * eb) * inv;
      attn_out[(size_t)bnI * 768 + h * 64 + d] = (bf16)val;
    }
  }
}

// ---------------------------------------------------------------- launch
extern "C" void kernel_launch(void* const* d_in, const int* in_sizes, int n_in,
                              void* d_out, int out_size, void* d_ws, size_t ws_size,
                              hipStream_t stream) {
  const float* x   = (const float*)d_in[0];
  const float* sim = (const float*)d_in[1];
  const float* Wq  = (const float*)d_in[2];
  const float* bq  = (const float*)d_in[3];
  const float* Wkv = (const float*)d_in[4];
  const float* bkv = (const float*)d_in[5];
  const float* Wp  = (const float*)d_in[6];
  const float* bp  = (const float*)d_in[7];
  float* out = (float*)d_out;

  char* ws = (char*)d_ws;
  size_t off = 0;
  auto carve = [&](size_t bytes) -> char* {
    char* p = ws + off;
    off = (off + bytes + 255) & ~(size_t)255;
    return p;
  };
  bf16*  xb    = (bf16*) carve((size_t)8192 * 768 * 2);
  bf16*  Wqkvt = (bf16*) carve((size_t)2304 * 768 * 2);
  bf16*  Wpt   = (bf16*) carve((size_t)768 * 768 * 2);
  bf16*  Wkvb  = (bf16*) carve((size_t)768 * 1536 * 2);
  float* bias1 = (float*)carve(2304 * 4);
  bf16*  qkv   = (bf16*) carve((size_t)8192 * 2304 * 2);
  float* msim  = (float*)carve((size_t)8192 * 12 * 4);
  float* lsim  = (float*)carve((size_t)8192 * 12 * 4);
  float* osim  = (float*)carve((size_t)8192 * 768 * 4);
  bf16*  attn  = (bf16*) carve((size_t)8192 * 768 * 2);
  size_t rem = (ws_size > off) ? ws_size - off : 0;
  int CH = 2048;                                   // (b,n) pairs per chunk
  while (CH > 128 && (size_t)CH * 18432 > rem) CH >>= 1;
  bf16* U = (bf16*)carve((size_t)CH * 12 * 768 * 2);   // U then S~ in place

  cast4_kernel<<<6144, 256, 0, stream>>>(x, xb, 8192 * 768 / 4);
  cast4_kernel<<<1152, 256, 0, stream>>>(Wkv, Wkvb, 768 * 1536 / 4);
  prep_weights<<<(2304 * 768 + 768 * 768 + 2304 + 255) / 256, 256, 0, stream>>>(
      Wq, Wkv, Wp, bq, bkv, Wqkvt, Wpt, bias1);
  // qkv = x @ [Wq|Wkv] + [bq|bkv]
  gemm_bt<<<dim3(18, 64), 256, 0, stream>>>(xb, Wqkvt, bias1, qkv, nullptr, 8192, 2304, 768);

  int nch = 8192 / CH;
  for (int c = 0; c < nch; c++) {
    int p0 = c * CH;
    // U[bn,h,:] = Q_h[bn,:] @ Wk_h^T   (12 thin GEMMs, K=64)
    gemm_bt_g<<<dim3(12, CH / 128, 12), 256, 0, stream>>>(
        qkv + (size_t)p0 * 2304, 2304, 64,
        Wkvb, 1536, 64,
        U, nullptr, 9216, 768,
        nullptr, 0, nullptr, 0, 64);
    // logits + softmax partials + S~ (in place over U)
    sim_logits<<<CH, 256, 0, stream>>>(sim + (size_t)p0 * 6144, U, qkv, bias1, p0, msim, lsim);
    // osim[bn, h*64+j] = S~_h @ Wv_h + lsim*bv   (12 thin GEMMs, N=64)
    gemm_bt_g<<<dim3(1, CH / 128, 12), 256, 0, stream>>>(
        U, 9216, 768,
        Wqkvt + (size_t)1536 * 768, 768, 64 * 768,
        nullptr, osim + (size_t)p0 * 768, 768, 64,
        bias1 + 1536, 64, lsim + (size_t)p0 * 12, 12, 768);
  }
  self_attn<<<1536, 256, 0, stream>>>(qkv, msim, lsim, osim, attn);
  // out = attn @ Wp + bp (fp32 out)
  gemm_bt<<<dim3(6, 64), 256, 0, stream>>>(attn, Wpt, bp, nullptr, out, 8192, 768, 768);
}

// Round 4
// 621.237 us; speedup vs baseline: 1.1611x; 1.1611x over previous
//
#include <hip/hip_runtime.h>

typedef __bf16 bf16;
typedef __bf16 bf16x8 __attribute__((ext_vector_type(8)));
typedef __bf16 bf16x4 __attribute__((ext_vector_type(4)));
typedef float  f32x4  __attribute__((ext_vector_type(4)));

#define SCALE 0.125f   // Dh^-0.5, exact in bf16

__device__ __forceinline__ void gl_lds16(const bf16* g, bf16* l) {
  __builtin_amdgcn_global_load_lds(
      (const __attribute__((address_space(1))) void*)g,
      (__attribute__((address_space(3))) void*)l, 16, 0, 0);
}

// ---------------------------------------------------------------- fused prep
// blocks [0,6144): cast x -> xb (bf16)
// blocks [6144,7296): cast Wkv -> Wkvb (bf16, row-major 768x1536)
// blocks [7296,...): build Wqkvt (2304x768) = [Wq|Wkv]^T, Wpt = Wp^T, bias1 = bq|bkv
__global__ __launch_bounds__(256) void prep_all(
    const float* __restrict__ x, const float* __restrict__ Wq,
    const float* __restrict__ Wkv, const float* __restrict__ Wp,
    const float* __restrict__ bq, const float* __restrict__ bkv,
    bf16* __restrict__ xb, bf16* __restrict__ Wqkvt, bf16* __restrict__ Wpt,
    bf16* __restrict__ Wkvb, float* __restrict__ bias1) {
  int bid = blockIdx.x;
  if (bid < 6144) {
    int i = bid * 256 + threadIdx.x;          // 1572864 float4 total, exact
    float4 v = ((const float4*)x)[i];
    bf16x4 o = { (bf16)v.x, (bf16)v.y, (bf16)v.z, (bf16)v.w };
    *(bf16x4*)(xb + (size_t)i * 4) = o;
  } else if (bid < 7296) {
    int i = (bid - 6144) * 256 + threadIdx.x; // 294912 float4, exact
    float4 v = ((const float4*)Wkv)[i];
    bf16x4 o = { (bf16)v.x, (bf16)v.y, (bf16)v.z, (bf16)v.w };
    *(bf16x4*)(Wkvb + (size_t)i * 4) = o;
  } else {
    int idx = (bid - 7296) * 256 + threadIdx.x;
    const int T1 = 2304 * 768, T2 = 768 * 768;
    if (idx < T1) {
      int c = idx / 768, j = idx - c * 768;
      float v = (c < 768) ? Wq[(size_t)j * 768 + c] : Wkv[(size_t)j * 1536 + (c - 768)];
      Wqkvt[idx] = (bf16)v;
    } else if (idx < T1 + T2) {
      int t2 = idx - T1;
      int c = t2 / 768, j = t2 - c * 768;
      Wpt[t2] = (bf16)Wp[(size_t)j * 768 + c];
    } else if (idx < T1 + T2 + 2304) {
      int c = idx - T1 - T2;
      bias1[c] = (c < 768) ? bq[c] : bkv[c - 768];
    }
  }
}

// ---------------------------------------------------------------- GEMM (A MxK, Bt NxK, bf16, fp32 acc)
// 128x128 tile, 4 waves in 2x2, each wave 64x64 = 4x4 mfma_f32_16x16x32_bf16 tiles.
__global__ __launch_bounds__(256) void gemm_bt(
    const bf16* __restrict__ A, const bf16* __restrict__ Bt,
    const float* __restrict__ bias,
    bf16* __restrict__ Cb, float* __restrict__ Cf,
    int Mdim, int Ndim, int Kdim) {
  __shared__ alignas(16) bf16 As[128 * 32];
  __shared__ alignas(16) bf16 Bs[128 * 32];
  int tid = threadIdx.x;
  int lane = tid & 63, wave = tid >> 6;
  int wr = wave >> 1, wc = wave & 1;
  int bm = blockIdx.y * 128, bn = blockIdx.x * 128;
  int lr = lane & 15, quad = lane >> 4;
  f32x4 acc[4][4] = {};
  for (int kb = 0; kb < Kdim; kb += 32) {
    __syncthreads();
#pragma unroll
    for (int i = 0; i < 2; i++) {
      int c = tid + i * 256;          // 512 16B-chunks per tile; LDS byte = c*16
      int r = c >> 2, cc = (c & 3) * 8;
      bf16* ldsbase_a = As + ((size_t)i * 256 + wave * 64) * 8;  // wave-uniform
      bf16* ldsbase_b = Bs + ((size_t)i * 256 + wave * 64) * 8;
      gl_lds16(A + (size_t)(bm + r) * Kdim + kb + cc, ldsbase_a);
      gl_lds16(Bt + (size_t)(bn + r) * Kdim + kb + cc, ldsbase_b);
    }
    __syncthreads();
    bf16x8 af[4], bg[4];
#pragma unroll
    for (int mi = 0; mi < 4; mi++)
      af[mi] = *(const bf16x8*)(As + (wr * 64 + mi * 16 + lr) * 32 + quad * 8);
#pragma unroll
    for (int ni = 0; ni < 4; ni++)
      bg[ni] = *(const bf16x8*)(Bs + (wc * 64 + ni * 16 + lr) * 32 + quad * 8);
#pragma unroll
    for (int mi = 0; mi < 4; mi++)
#pragma unroll
      for (int ni = 0; ni < 4; ni++)
        acc[mi][ni] = __builtin_amdgcn_mfma_f32_16x16x32_bf16(af[mi], bg[ni], acc[mi][ni], 0, 0, 0);
  }
#pragma unroll
  for (int mi = 0; mi < 4; mi++)
#pragma unroll
    for (int ni = 0; ni < 4; ni++)
#pragma unroll
      for (int r = 0; r < 4; r++) {
        int row = bm + wr * 64 + mi * 16 + quad * 4 + r;
        int col = bn + wc * 64 + ni * 16 + lr;
        float v = acc[mi][ni][r] + bias[col];
        if (Cb) Cb[(size_t)row * Ndim + col] = (bf16)v;
        else    Cf[(size_t)row * Ndim + col] = v;
      }
}

// ---------------------------------------------------------------- generalized thin GEMM
// 128(M) x 64(N) tile, 4 waves 2x2 (each 64x32). Strided A/B/C with per-z offsets
// for batched-per-head use. Optional epilogue: C += bias[z*biasZ+col] * rowscale[row*rsLd+z].
__global__ __launch_bounds__(256) void gemm_bt_g(
    const bf16* __restrict__ A, int lda, int aZ,
    const bf16* __restrict__ Bt, int ldb, int bZ,
    bf16* __restrict__ Cb, float* __restrict__ Cf, int ldc, int cZ,
    const float* __restrict__ bias, int biasZ,
    const float* __restrict__ rowscale, int rsLd,
    int Kdim) {
  __shared__ alignas(16) bf16 As[128 * 32];
  __shared__ alignas(16) bf16 Bs[64 * 32];
  int tid = threadIdx.x;
  int lane = tid & 63, wave = tid >> 6;
  int wr = wave >> 1, wc = wave & 1;
  int bm = blockIdx.y * 128, bn = blockIdx.x * 64;
  int z = blockIdx.z;
  const bf16* Ab = A + (size_t)z * aZ;
  const bf16* Bb = Bt + (size_t)z * bZ;
  int lr = lane & 15, quad = lane >> 4;
  f32x4 acc[4][2] = {};
  for (int kb = 0; kb < Kdim; kb += 32) {
    __syncthreads();
#pragma unroll
    for (int i = 0; i < 2; i++) {
      int c = tid + i * 256;
      int r = c >> 2, cc = (c & 3) * 8;
      gl_lds16(Ab + (size_t)(bm + r) * lda + kb + cc,
               As + ((size_t)i * 256 + wave * 64) * 8);
    }
    {
      int r = tid >> 2, cc = (tid & 3) * 8;
      gl_lds16(Bb + (size_t)(bn + r) * ldb + kb + cc,
               Bs + (size_t)(wave * 64) * 8);
    }
    __syncthreads();
    bf16x8 af[4], bg[2];
#pragma unroll
    for (int mi = 0; mi < 4; mi++)
      af[mi] = *(const bf16x8*)(As + (wr * 64 + mi * 16 + lr) * 32 + quad * 8);
#pragma unroll
    for (int ni = 0; ni < 2; ni++)
      bg[ni] = *(const bf16x8*)(Bs + (wc * 32 + ni * 16 + lr) * 32 + quad * 8);
#pragma unroll
    for (int mi = 0; mi < 4; mi++)
#pragma unroll
      for (int ni = 0; ni < 2; ni++)
        acc[mi][ni] = __builtin_amdgcn_mfma_f32_16x16x32_bf16(af[mi], bg[ni], acc[mi][ni], 0, 0, 0);
  }
#pragma unroll
  for (int mi = 0; mi < 4; mi++)
#pragma unroll
    for (int ni = 0; ni < 2; ni++)
#pragma unroll
      for (int r = 0; r < 4; r++) {
        int row = bm + wr * 64 + mi * 16 + quad * 4 + r;
        int col = wc * 32 + ni * 16 + lr;
        float v = acc[mi][ni][r];
        if (bias) {
          float sc = rowscale ? rowscale[(size_t)row * rsLd + z] : 1.f;
          v += bias[z * biasZ + col] * sc;
        }
        size_t idx = (size_t)row * ldc + (size_t)z * cZ + bn + col;
        if (Cb) Cb[idx] = (bf16)v;
        else    Cf[idx] = v;
      }
}

// ---------------------------------------------------------------- sim logits + softmax + weighted-sim
// One block per (b,n) pair. Reads fp32 sim directly (no cast pass) and U[bn,h,:]=Wk_h q_h;
// logits[h,m] = sim_m . U_h (+ q_h.bk_h); softmax over m -> msim,lsim; then overwrites U
// in place with S~[h,:] = sum_m w[h,m] sim_m (feeds O-GEMM: osim = S~ @ Wv + lsim*bv).
__global__ __launch_bounds__(256) void sim_logits(
    const float* __restrict__ sim,      // chunk base: [CH][8][768] fp32
    bf16* __restrict__ U,               // chunk base: [CH][12][768] bf16 (read, then S~ written)
    const bf16* __restrict__ qkv,
    const float* __restrict__ bias1,
    int bn0,
    float* __restrict__ msim, float* __restrict__ lsim) {
  __shared__ alignas(16) float simS[8][772];   // +4 pad: m-stride -> 4 banks
  __shared__ alignas(16) bf16  uS[12][776];    // +8 pad: h-stride -> 4 banks
  __shared__ float logitS[12][8];
  __shared__ float wS[12][8];
  __shared__ float cS[12];
  int t = threadIdx.x;
  int pair = blockIdx.x;
  int bn = bn0 + pair;
  // load sim fp32 (8x768 = 1536 float4)
  const float4* s4 = (const float4*)(sim + (size_t)pair * 6144);
#pragma unroll
  for (int ii = 0; ii < 6; ii++) {
    int i = t + ii * 256;
    float4 v = s4[i];
    int m = i / 192, jj = (i - m * 192) * 4;
    *(float4*)(&simS[m][jj]) = v;
  }
  // load U bf16 (12x768 = 1152 int4)
  const int4* u4 = (const int4*)(U + (size_t)pair * 9216);
  for (int i = t; i < 1152; i += 256) {
    int h = i / 96, c8 = (i - h * 96) * 8;
    *(int4*)(&uS[h][c8]) = u4[i];
  }
  // bias constant c_h = q_h . bk_h (zero when bkv==0, kept for generality)
  if (t < 96) {
    int h = t >> 3, d0 = (t & 7) * 8;
    bf16 qq[8];
    *(int4*)qq = *(const int4*)(qkv + (size_t)bn * 2304 + h * 64 + d0);
    float s = 0.f;
#pragma unroll
    for (int e = 0; e < 8; e++) s += (float)qq[e] * bias1[768 + h * 64 + d0 + e];
    s += __shfl_xor(s, 1, 64);
    s += __shfl_xor(s, 2, 64);
    s += __shfl_xor(s, 4, 64);
    if ((t & 7) == 0) cS[h] = s;
  }
  __syncthreads();
  // logits: 96 dots of length 768, 2 threads/dot on interleaved 8-elem chunks
  if (t < 192) {
    int hm = t >> 1, half = t & 1;
    int h = hm >> 3, m = hm & 7;
    float s = 0.f;
#pragma unroll 8
    for (int kk = 0; kk < 48; kk++) {
      int j0 = kk * 16 + half * 8;
      bf16x8 uv = *(const bf16x8*)(&uS[h][j0]);
      float4 a = *(const float4*)(&simS[m][j0]);
      float4 b = *(const float4*)(&simS[m][j0 + 4]);
      s += a.x * (float)uv[0] + a.y * (float)uv[1] + a.z * (float)uv[2] + a.w * (float)uv[3]
         + b.x * (float)uv[4] + b.y * (float)uv[5] + b.z * (float)uv[6] + b.w * (float)uv[7];
    }
    s += __shfl_xor(s, 1, 64);
    if (!half) logitS[h][m] = (s + cS[h]) * SCALE;
  }
  __syncthreads();
  if (t < 12) {
    float mx = logitS[t][0];
#pragma unroll
    for (int m = 1; m < 8; m++) mx = fmaxf(mx, logitS[t][m]);
    float l = 0.f;
#pragma unroll
    for (int m = 0; m < 8; m++) { float e = __expf(logitS[t][m] - mx); wS[t][m] = e; l += e; }
    msim[(size_t)bn * 12 + t] = mx;
    lsim[(size_t)bn * 12 + t] = l;
  }
  __syncthreads();
  // S~[h][j] = sum_m w[h][m] * sim[m][j]  -> overwrite U (paired bf16 stores)
  bf16* Sw = U + (size_t)pair * 9216;
  for (int i = t; i < 4608; i += 256) {
    int h = i / 384, j2 = (i - h * 384) * 2;
    float s0 = 0.f, s1 = 0.f;
#pragma unroll
    for (int m = 0; m < 8; m++) {
      float w = wS[h][m];
      s0 += w * simS[m][j2];
      s1 += w * simS[m][j2 + 1];
    }
    bf16 pr[2] = { (bf16)s0, (bf16)s1 };
    *(unsigned*)(&Sw[(size_t)h * 768 + j2]) = *(unsigned*)pr;
  }
}

// ---------------------------------------------------------------- self attention + merge (flash-style)
__global__ __launch_bounds__(256) void self_attn(
    const bf16* __restrict__ qkv,
    const float* __restrict__ msim, const float* __restrict__ lsim,
    const float* __restrict__ osim,
    bf16* __restrict__ attn_out) {
  __shared__ alignas(16) bf16 Ks[128][72];     // K tile rows (j,d)
  __shared__ alignas(16) bf16 Vt[64][136];     // V^T tile (d, j)
  __shared__ alignas(16) bf16 Ps[4][16][136];  // per-wave P strip (qrow, j)
  int bid = blockIdx.x;
  int qc = bid & 7;
  int h  = (bid >> 3) % 12;
  int b  = bid / 96;
  int rowbase = b * 512;
  int q0 = qc * 64;
  int t = threadIdx.x, lane = t & 63, wv = t >> 6;
  int lr = lane & 15, quad = lane >> 4;

  const bf16* qrow = qkv + (size_t)(rowbase + q0 + wv * 16 + lr) * 2304 + h * 64;
  bf16x8 aq0 = *(const bf16x8*)(qrow + quad * 8);
  bf16x8 aq1 = *(const bf16x8*)(qrow + 32 + quad * 8);

  f32x4 oacc[4] = {};
  float mrow[4], lrow[4];
#pragma unroll
  for (int r = 0; r < 4; r++) { mrow[r] = -1e30f; lrow[r] = 0.f; }

  for (int kt = 0; kt < 4; kt++) {
    int jb = kt * 128;
    __syncthreads();
    for (int ci = t; ci < 1024; ci += 256) {
      int j = ci >> 3, off = (ci & 7) * 8;
      *(int4*)(&Ks[j][off]) =
          *(const int4*)(qkv + (size_t)(rowbase + jb + j) * 2304 + 768 + h * 64 + off);
    }
    for (int ci = t; ci < 512; ci += 256) {
      int jp = ci >> 3, off = (ci & 7) * 8;
      const bf16* v0 = qkv + (size_t)(rowbase + jb + jp * 2) * 2304 + 1536 + h * 64 + off;
      bf16 ta[8], tb[8];
      *(int4*)ta = *(const int4*)v0;
      *(int4*)tb = *(const int4*)(v0 + 2304);
#pragma unroll
      for (int e = 0; e < 8; e++) {
        bf16 pr[2] = { ta[e], tb[e] };
        *(unsigned*)(&Vt[off + e][jp * 2]) = *(unsigned*)pr;
      }
    }
    __syncthreads();

    f32x4 sacc[8] = {};
#pragma unroll
    for (int ni = 0; ni < 8; ni++) {
      int jj = ni * 16 + lr;
      bf16x8 bk0 = *(const bf16x8*)(&Ks[jj][quad * 8]);
      bf16x8 bk1 = *(const bf16x8*)(&Ks[jj][32 + quad * 8]);
      sacc[ni] = __builtin_amdgcn_mfma_f32_16x16x32_bf16(aq0, bk0, sacc[ni], 0, 0, 0);
      sacc[ni] = __builtin_amdgcn_mfma_f32_16x16x32_bf16(aq1, bk1, sacc[ni], 0, 0, 0);
    }
    float tm[4];
#pragma unroll
    for (int r = 0; r < 4; r++) {
      float v = sacc[0][r];
#pragma unroll
      for (int ni = 1; ni < 8; ni++) v = fmaxf(v, sacc[ni][r]);
      tm[r] = v;
    }
#pragma unroll
    for (int s = 1; s < 16; s <<= 1)
#pragma unroll
      for (int r = 0; r < 4; r++) tm[r] = fmaxf(tm[r], __shfl_xor(tm[r], s, 64));
    float alpha[4], s4[4];
#pragma unroll
    for (int r = 0; r < 4; r++) {
      float mnew = fmaxf(mrow[r], tm[r] * SCALE);
      alpha[r] = __expf(mrow[r] - mnew);
      mrow[r] = mnew;
      s4[r] = 0.f;
    }
#pragma unroll
    for (int ni = 0; ni < 8; ni++)
#pragma unroll
      for (int r = 0; r < 4; r++) {
        float p = __expf(sacc[ni][r] * SCALE - mrow[r]);
        s4[r] += p;
        Ps[wv][quad * 4 + r][ni * 16 + lr] = (bf16)p;
      }
#pragma unroll
    for (int s = 1; s < 16; s <<= 1)
#pragma unroll
      for (int r = 0; r < 4; r++) s4[r] += __shfl_xor(s4[r], s, 64);
#pragma unroll
    for (int r = 0; r < 4; r++) lrow[r] = lrow[r] * alpha[r] + s4[r];
#pragma unroll
    for (int ni = 0; ni < 4; ni++)
#pragma unroll
      for (int r = 0; r < 4; r++) oacc[ni][r] *= alpha[r];

#pragma unroll
    for (int kb = 0; kb < 4; kb++) {
      bf16x8 ap = *(const bf16x8*)(&Ps[wv][lr][kb * 32 + quad * 8]);
#pragma unroll
      for (int ni = 0; ni < 4; ni++) {
        bf16x8 bv = *(const bf16x8*)(&Vt[ni * 16 + lr][kb * 32 + quad * 8]);
        oacc[ni] = __builtin_amdgcn_mfma_f32_16x16x32_bf16(ap, bv, oacc[ni], 0, 0, 0);
      }
    }
  }

#pragma unroll
  for (int r = 0; r < 4; r++) {
    int bnI = rowbase + q0 + wv * 16 + quad * 4 + r;
    float ms = msim[(size_t)bnI * 12 + h], ls = lsim[(size_t)bnI * 12 + h];
    float mt = fmaxf(mrow[r], ms);
    float ea = __expf(mrow[r] - mt), eb = __expf(ms - mt);
    float inv = 1.f / (lrow[r] * ea + ls * eb);
#pragma unroll
    for (int ni = 0; ni < 4; ni++) {
      int d = ni * 16 + lr;
      float val = (oacc[ni][r] * ea + osim[(size_t)bnI * 768 + h * 64 + d] * eb) * inv;
      attn_out[(size_t)bnI * 768 + h * 64 + d] = (bf16)val;
    }
  }
}

// ---------------------------------------------------------------- launch
extern "C" void kernel_launch(void* const* d_in, const int* in_sizes, int n_in,
                              void* d_out, int out_size, void* d_ws, size_t ws_size,
                              hipStream_t stream) {
  const float* x   = (const float*)d_in[0];
  const float* sim = (const float*)d_in[1];
  const float* Wq  = (const float*)d_in[2];
  const float* bq  = (const float*)d_in[3];
  const float* Wkv = (const float*)d_in[4];
  const float* bkv = (const float*)d_in[5];
  const float* Wp  = (const float*)d_in[6];
  const float* bp  = (const float*)d_in[7];
  float* out = (float*)d_out;

  char* ws = (char*)d_ws;
  size_t off = 0;
  auto carve = [&](size_t bytes) -> char* {
    char* p = ws + off;
    off = (off + bytes + 255) & ~(size_t)255;
    return p;
  };
  bf16*  xb    = (bf16*) carve((size_t)8192 * 768 * 2);
  bf16*  Wqkvt = (bf16*) carve((size_t)2304 * 768 * 2);
  bf16*  Wpt   = (bf16*) carve((size_t)768 * 768 * 2);
  bf16*  Wkvb  = (bf16*) carve((size_t)768 * 1536 * 2);
  float* bias1 = (float*)carve(2304 * 4);
  bf16*  qkv   = (bf16*) carve((size_t)8192 * 2304 * 2);
  float* msim  = (float*)carve((size_t)8192 * 12 * 4);
  float* lsim  = (float*)carve((size_t)8192 * 12 * 4);
  float* osim  = (float*)carve((size_t)8192 * 768 * 4);
  bf16*  attn  = (bf16*) carve((size_t)8192 * 768 * 2);
  size_t rem = (ws_size > off) ? ws_size - off : 0;
  int CH = 8192;                                   // (b,n) pairs per chunk (prefer one-shot)
  while (CH > 128 && (size_t)CH * 18432 > rem) CH >>= 1;
  bf16* U = (bf16*)carve((size_t)CH * 12 * 768 * 2);   // U then S~ in place

  // fused prep: x-cast | Wkv-cast | weight transposes + bias pack
  prep_all<<<16521, 256, 0, stream>>>(x, Wq, Wkv, Wp, bq, bkv, xb, Wqkvt, Wpt, Wkvb, bias1);
  // qkv = x @ [Wq|Wkv] + [bq|bkv]
  gemm_bt<<<dim3(18, 64), 256, 0, stream>>>(xb, Wqkvt, bias1, qkv, nullptr, 8192, 2304, 768);

  int nch = 8192 / CH;
  for (int c = 0; c < nch; c++) {
    int p0 = c * CH;
    // U[bn,h,:] = Q_h[bn,:] @ Wk_h^T   (12 thin GEMMs, K=64)
    gemm_bt_g<<<dim3(12, CH / 128, 12), 256, 0, stream>>>(
        qkv + (size_t)p0 * 2304, 2304, 64,
        Wkvb, 1536, 64,
        U, nullptr, 9216, 768,
        nullptr, 0, nullptr, 0, 64);
    // logits + softmax partials + S~ (in place over U)
    sim_logits<<<CH, 256, 0, stream>>>(sim + (size_t)p0 * 6144, U, qkv, bias1, p0, msim, lsim);
    // osim[bn, h*64+j] = S~_h @ Wv_h + lsim*bv   (12 thin GEMMs, N=64)
    gemm_bt_g<<<dim3(1, CH / 128, 12), 256, 0, stream>>>(
        U, 9216, 768,
        Wqkvt + (size_t)1536 * 768, 768, 64 * 768,
        nullptr, osim + (size_t)p0 * 768, 768, 64,
        bias1 + 1536, 64, lsim + (size_t)p0 * 12, 12, 768);
  }
  self_attn<<<1536, 256, 0, stream>>>(qkv, msim, lsim, osim, attn);
  // out = attn @ Wp + bp (fp32 out)
  gemm_bt<<<dim3(6, 64), 256, 0, stream>>>(attn, Wpt, bp, nullptr, out, 8192, 768, 768);
}

// Round 5
// 606.880 us; speedup vs baseline: 1.1886x; 1.0237x over previous
//
#include <hip/hip_runtime.h>

typedef __bf16 bf16;
typedef __bf16 bf16x8 __attribute__((ext_vector_type(8)));
typedef __bf16 bf16x4 __attribute__((ext_vector_type(4)));
typedef float  f32x4  __attribute__((ext_vector_type(4)));

#define SCALE 0.125f   // Dh^-0.5, exact in bf16

__device__ __forceinline__ void gl_lds16(const bf16* g, bf16* l) {
  __builtin_amdgcn_global_load_lds(
      (const __attribute__((address_space(1))) void*)g,
      (__attribute__((address_space(3))) void*)l, 16, 0, 0);
}

// ---------------------------------------------------------------- fused prep
// blocks [0,6144): cast x -> xb (bf16)
// blocks [6144,7296): cast Wkv -> Wkvb (bf16, row-major 768x1536)
// blocks [7296,...): build Wqkvt (2304x768) = [Wq|Wkv]^T, Wpt = Wp^T, bias1 = bq|bkv
__global__ __launch_bounds__(256) void prep_all(
    const float* __restrict__ x, const float* __restrict__ Wq,
    const float* __restrict__ Wkv, const float* __restrict__ Wp,
    const float* __restrict__ bq, const float* __restrict__ bkv,
    bf16* __restrict__ xb, bf16* __restrict__ Wqkvt, bf16* __restrict__ Wpt,
    bf16* __restrict__ Wkvb, float* __restrict__ bias1) {
  int bid = blockIdx.x;
  if (bid < 6144) {
    int i = bid * 256 + threadIdx.x;          // 1572864 float4 total, exact
    float4 v = ((const float4*)x)[i];
    bf16x4 o = { (bf16)v.x, (bf16)v.y, (bf16)v.z, (bf16)v.w };
    *(bf16x4*)(xb + (size_t)i * 4) = o;
  } else if (bid < 7296) {
    int i = (bid - 6144) * 256 + threadIdx.x; // 294912 float4, exact
    float4 v = ((const float4*)Wkv)[i];
    bf16x4 o = { (bf16)v.x, (bf16)v.y, (bf16)v.z, (bf16)v.w };
    *(bf16x4*)(Wkvb + (size_t)i * 4) = o;
  } else {
    int idx = (bid - 7296) * 256 + threadIdx.x;
    const int T1 = 2304 * 768, T2 = 768 * 768;
    if (idx < T1) {
      int c = idx / 768, j = idx - c * 768;
      float v = (c < 768) ? Wq[(size_t)j * 768 + c] : Wkv[(size_t)j * 1536 + (c - 768)];
      Wqkvt[idx] = (bf16)v;
    } else if (idx < T1 + T2) {
      int t2 = idx - T1;
      int c = t2 / 768, j = t2 - c * 768;
      Wpt[t2] = (bf16)Wp[(size_t)j * 768 + c];
    } else if (idx < T1 + T2 + 2304) {
      int c = idx - T1 - T2;
      bias1[c] = (c < 768) ? bq[c] : bkv[c - 768];
    }
  }
}

// ---------------------------------------------------------------- GEMM (A MxK, Bt NxK, bf16, fp32 acc)
// 128x128 tile, 4 waves in 2x2, each wave 64x64 = 4x4 mfma_f32_16x16x32_bf16 tiles.
__global__ __launch_bounds__(256) void gemm_bt(
    const bf16* __restrict__ A, const bf16* __restrict__ Bt,
    const float* __restrict__ bias,
    bf16* __restrict__ Cb, float* __restrict__ Cf,
    int Mdim, int Ndim, int Kdim) {
  __shared__ alignas(16) bf16 As[128 * 32];
  __shared__ alignas(16) bf16 Bs[128 * 32];
  int tid = threadIdx.x;
  int lane = tid & 63, wave = tid >> 6;
  int wr = wave >> 1, wc = wave & 1;
  int bm = blockIdx.y * 128, bn = blockIdx.x * 128;
  int lr = lane & 15, quad = lane >> 4;
  f32x4 acc[4][4] = {};
  for (int kb = 0; kb < Kdim; kb += 32) {
    __syncthreads();
#pragma unroll
    for (int i = 0; i < 2; i++) {
      int c = tid + i * 256;          // 512 16B-chunks per tile; LDS byte = c*16
      int r = c >> 2, cc = (c & 3) * 8;
      bf16* ldsbase_a = As + ((size_t)i * 256 + wave * 64) * 8;  // wave-uniform
      bf16* ldsbase_b = Bs + ((size_t)i * 256 + wave * 64) * 8;
      gl_lds16(A + (size_t)(bm + r) * Kdim + kb + cc, ldsbase_a);
      gl_lds16(Bt + (size_t)(bn + r) * Kdim + kb + cc, ldsbase_b);
    }
    __syncthreads();
    bf16x8 af[4], bg[4];
#pragma unroll
    for (int mi = 0; mi < 4; mi++)
      af[mi] = *(const bf16x8*)(As + (wr * 64 + mi * 16 + lr) * 32 + quad * 8);
#pragma unroll
    for (int ni = 0; ni < 4; ni++)
      bg[ni] = *(const bf16x8*)(Bs + (wc * 64 + ni * 16 + lr) * 32 + quad * 8);
#pragma unroll
    for (int mi = 0; mi < 4; mi++)
#pragma unroll
      for (int ni = 0; ni < 4; ni++)
        acc[mi][ni] = __builtin_amdgcn_mfma_f32_16x16x32_bf16(af[mi], bg[ni], acc[mi][ni], 0, 0, 0);
  }
#pragma unroll
  for (int mi = 0; mi < 4; mi++)
#pragma unroll
    for (int ni = 0; ni < 4; ni++)
#pragma unroll
      for (int r = 0; r < 4; r++) {
        int row = bm + wr * 64 + mi * 16 + quad * 4 + r;
        int col = bn + wc * 64 + ni * 16 + lr;
        float v = acc[mi][ni][r] + bias[col];
        if (Cb) Cb[(size_t)row * Ndim + col] = (bf16)v;
        else    Cf[(size_t)row * Ndim + col] = v;
      }
}

// ---------------------------------------------------------------- generalized thin GEMM
// 128(M) x 64(N) tile, 4 waves 2x2 (each 64x32). Strided A/B/C with per-z offsets
// for batched-per-head use. Optional epilogue: C += bias[z*biasZ+col] * rowscale[row*rsLd+z].
__global__ __launch_bounds__(256) void gemm_bt_g(
    const bf16* __restrict__ A, int lda, int aZ,
    const bf16* __restrict__ Bt, int ldb, int bZ,
    bf16* __restrict__ Cb, float* __restrict__ Cf, int ldc, int cZ,
    const float* __restrict__ bias, int biasZ,
    const float* __restrict__ rowscale, int rsLd,
    int Kdim) {
  __shared__ alignas(16) bf16 As[128 * 32];
  __shared__ alignas(16) bf16 Bs[64 * 32];
  int tid = threadIdx.x;
  int lane = tid & 63, wave = tid >> 6;
  int wr = wave >> 1, wc = wave & 1;
  int bm = blockIdx.y * 128, bn = blockIdx.x * 64;
  int z = blockIdx.z;
  const bf16* Ab = A + (size_t)z * aZ;
  const bf16* Bb = Bt + (size_t)z * bZ;
  int lr = lane & 15, quad = lane >> 4;
  f32x4 acc[4][2] = {};
  for (int kb = 0; kb < Kdim; kb += 32) {
    __syncthreads();
#pragma unroll
    for (int i = 0; i < 2; i++) {
      int c = tid + i * 256;
      int r = c >> 2, cc = (c & 3) * 8;
      gl_lds16(Ab + (size_t)(bm + r) * lda + kb + cc,
               As + ((size_t)i * 256 + wave * 64) * 8);
    }
    {
      int r = tid >> 2, cc = (tid & 3) * 8;
      gl_lds16(Bb + (size_t)(bn + r) * ldb + kb + cc,
               Bs + (size_t)(wave * 64) * 8);
    }
    __syncthreads();
    bf16x8 af[4], bg[2];
#pragma unroll
    for (int mi = 0; mi < 4; mi++)
      af[mi] = *(const bf16x8*)(As + (wr * 64 + mi * 16 + lr) * 32 + quad * 8);
#pragma unroll
    for (int ni = 0; ni < 2; ni++)
      bg[ni] = *(const bf16x8*)(Bs + (wc * 32 + ni * 16 + lr) * 32 + quad * 8);
#pragma unroll
    for (int mi = 0; mi < 4; mi++)
#pragma unroll
      for (int ni = 0; ni < 2; ni++)
        acc[mi][ni] = __builtin_amdgcn_mfma_f32_16x16x32_bf16(af[mi], bg[ni], acc[mi][ni], 0, 0, 0);
  }
#pragma unroll
  for (int mi = 0; mi < 4; mi++)
#pragma unroll
    for (int ni = 0; ni < 2; ni++)
#pragma unroll
      for (int r = 0; r < 4; r++) {
        int row = bm + wr * 64 + mi * 16 + quad * 4 + r;
        int col = wc * 32 + ni * 16 + lr;
        float v = acc[mi][ni][r];
        if (bias) {
          float sc = rowscale ? rowscale[(size_t)row * rsLd + z] : 1.f;
          v += bias[z * biasZ + col] * sc;
        }
        size_t idx = (size_t)row * ldc + (size_t)z * cZ + bn + col;
        if (Cb) Cb[idx] = (bf16)v;
        else    Cf[idx] = v;
      }
}

// ---------------------------------------------------------------- sim logits + softmax + weighted-sim
// One block per (b,n) pair. sim staged ONCE in LDS as bf16 [8][784] (~13 KB -> 8 blocks/CU);
// logits read U rows straight from global (L2/L3-hot, 16 threads broadcast per row);
// softmax fused into the logit phase via dup-safe shfl_xor{2,4,8}; S~ overwrites U in place.
__global__ __launch_bounds__(256) void sim_logits(
    const float* __restrict__ sim,      // [8192][8][768] fp32
    bf16* __restrict__ U,               // [8192][12][768] bf16 (read, then S~ written)
    const bf16* __restrict__ qkv,
    const float* __restrict__ bias1,
    int bn0,
    float* __restrict__ msim, float* __restrict__ lsim) {
  __shared__ alignas(16) bf16 simS[8][784];    // row stride 1568B: 16B reads conflict-free
  __shared__ float wS[12][8];
  __shared__ float cS[12];
  int t = threadIdx.x;
  int pair = blockIdx.x;
  int bn = bn0 + pair;
  // load sim fp32 -> bf16 LDS (8x768 = 1536 float4, 6 per thread, exact)
  const float4* s4 = (const float4*)(sim + (size_t)pair * 6144);
#pragma unroll
  for (int ii = 0; ii < 6; ii++) {
    int i = t + ii * 256;
    float4 v = s4[i];
    int m = i / 192, jj = (i - m * 192) * 4;
    bf16x4 o = { (bf16)v.x, (bf16)v.y, (bf16)v.z, (bf16)v.w };
    *(bf16x4*)(&simS[m][jj]) = o;
  }
  // bias constant c_h = q_h . bk_h (zero when bkv==0, kept for generality)
  if (t < 96) {
    int h = t >> 3, d0 = (t & 7) * 8;
    bf16 qq[8];
    *(int4*)qq = *(const int4*)(qkv + (size_t)bn * 2304 + h * 64 + d0);
    float s = 0.f;
#pragma unroll
    for (int e = 0; e < 8; e++) s += (float)qq[e] * bias1[768 + h * 64 + d0 + e];
    s += __shfl_xor(s, 1, 64);
    s += __shfl_xor(s, 2, 64);
    s += __shfl_xor(s, 4, 64);
    if ((t & 7) == 0) cS[h] = s;
  }
  __syncthreads();
  // logits + softmax: t<192, thread = (h, m, half); dot split across lane pairs.
  if (t < 192) {
    int hm = t >> 1, half = t & 1;
    int h = hm >> 3, m = hm & 7;
    const bf16* Urow = U + (size_t)pair * 9216 + (size_t)h * 768;
    float s = 0.f;
#pragma unroll 4
    for (int kk = 0; kk < 48; kk++) {
      int j0 = kk * 16 + half * 8;
      bf16x8 uv = *(const bf16x8*)(Urow + j0);
      bf16x8 sv = *(const bf16x8*)(&simS[m][j0]);
#pragma unroll
      for (int e = 0; e < 8; e++) s += (float)uv[e] * (float)sv[e];
    }
    s += __shfl_xor(s, 1, 64);          // both halves now hold the full dot
    s = (s + cS[h]) * SCALE;
    // max over the 8 m within this h's 16-lane group (values duplicated in pairs):
    float mx = s;
    mx = fmaxf(mx, __shfl_xor(mx, 2, 64));
    mx = fmaxf(mx, __shfl_xor(mx, 4, 64));
    mx = fmaxf(mx, __shfl_xor(mx, 8, 64));
    float e = __expf(s - mx);
    float l = e;
    l += __shfl_xor(l, 2, 64);          // dup-safe: each m counted exactly once
    l += __shfl_xor(l, 4, 64);
    l += __shfl_xor(l, 8, 64);
    if ((t & 15) == 0) {                // one lane per h (h = t>>4, 12 of them)
      msim[(size_t)bn * 12 + h] = mx;
      lsim[(size_t)bn * 12 + h] = l;
    }
    wS[h][m] = e;                        // pair-duplicate write, same value
  }
  __syncthreads();
  // S~[h][j] = sum_m w[h][m] * sim[m][j]  -> overwrite U (paired bf16 stores)
  bf16* Sw = U + (size_t)pair * 9216;
  for (int i = t; i < 4608; i += 256) {
    int h = i / 384, j2 = (i - h * 384) * 2;
    float s0 = 0.f, s1 = 0.f;
#pragma unroll
    for (int m = 0; m < 8; m++) {
      float w = wS[h][m];
      s0 += w * (float)simS[m][j2];
      s1 += w * (float)simS[m][j2 + 1];
    }
    bf16 pr[2] = { (bf16)s0, (bf16)s1 };
    *(unsigned*)(&Sw[(size_t)h * 768 + j2]) = *(unsigned*)pr;
  }
}

// ---------------------------------------------------------------- self attention + merge (flash-style)
__global__ __launch_bounds__(256) void self_attn(
    const bf16* __restrict__ qkv,
    const float* __restrict__ msim, const float* __restrict__ lsim,
    const float* __restrict__ osim,
    bf16* __restrict__ attn_out) {
  __shared__ alignas(16) bf16 Ks[128][72];     // K tile rows (j,d)
  __shared__ alignas(16) bf16 Vt[64][136];     // V^T tile (d, j)
  __shared__ alignas(16) bf16 Ps[4][16][136];  // per-wave P strip (qrow, j)
  int bid = blockIdx.x;
  int qc = bid & 7;
  int h  = (bid >> 3) % 12;
  int b  = bid / 96;
  int rowbase = b * 512;
  int q0 = qc * 64;
  int t = threadIdx.x, lane = t & 63, wv = t >> 6;
  int lr = lane & 15, quad = lane >> 4;

  const bf16* qrow = qkv + (size_t)(rowbase + q0 + wv * 16 + lr) * 2304 + h * 64;
  bf16x8 aq0 = *(const bf16x8*)(qrow + quad * 8);
  bf16x8 aq1 = *(const bf16x8*)(qrow + 32 + quad * 8);

  f32x4 oacc[4] = {};
  float mrow[4], lrow[4];
#pragma unroll
  for (int r = 0; r < 4; r++) { mrow[r] = -1e30f; lrow[r] = 0.f; }

  for (int kt = 0; kt < 4; kt++) {
    int jb = kt * 128;
    __syncthreads();
    for (int ci = t; ci < 1024; ci += 256) {
      int j = ci >> 3, off = (ci & 7) * 8;
      *(int4*)(&Ks[j][off]) =
          *(const int4*)(qkv + (size_t)(rowbase + jb + j) * 2304 + 768 + h * 64 + off);
    }
    for (int ci = t; ci < 512; ci += 256) {
      int jp = ci >> 3, off = (ci & 7) * 8;
      const bf16* v0 = qkv + (size_t)(rowbase + jb + jp * 2) * 2304 + 1536 + h * 64 + off;
      bf16 ta[8], tb[8];
      *(int4*)ta = *(const int4*)v0;
      *(int4*)tb = *(const int4*)(v0 + 2304);
#pragma unroll
      for (int e = 0; e < 8; e++) {
        bf16 pr[2] = { ta[e], tb[e] };
        *(unsigned*)(&Vt[off + e][jp * 2]) = *(unsigned*)pr;
      }
    }
    __syncthreads();

    f32x4 sacc[8] = {};
#pragma unroll
    for (int ni = 0; ni < 8; ni++) {
      int jj = ni * 16 + lr;
      bf16x8 bk0 = *(const bf16x8*)(&Ks[jj][quad * 8]);
      bf16x8 bk1 = *(const bf16x8*)(&Ks[jj][32 + quad * 8]);
      sacc[ni] = __builtin_amdgcn_mfma_f32_16x16x32_bf16(aq0, bk0, sacc[ni], 0, 0, 0);
      sacc[ni] = __builtin_amdgcn_mfma_f32_16x16x32_bf16(aq1, bk1, sacc[ni], 0, 0, 0);
    }
    float tm[4];
#pragma unroll
    for (int r = 0; r < 4; r++) {
      float v = sacc[0][r];
#pragma unroll
      for (int ni = 1; ni < 8; ni++) v = fmaxf(v, sacc[ni][r]);
      tm[r] = v;
    }
#pragma unroll
    for (int s = 1; s < 16; s <<= 1)
#pragma unroll
      for (int r = 0; r < 4; r++) tm[r] = fmaxf(tm[r], __shfl_xor(tm[r], s, 64));
    float alpha[4], s4[4];
#pragma unroll
    for (int r = 0; r < 4; r++) {
      float mnew = fmaxf(mrow[r], tm[r] * SCALE);
      alpha[r] = __expf(mrow[r] - mnew);
      mrow[r] = mnew;
      s4[r] = 0.f;
    }
#pragma unroll
    for (int ni = 0; ni < 8; ni++)
#pragma unroll
      for (int r = 0; r < 4; r++) {
        float p = __expf(sacc[ni][r] * SCALE - mrow[r]);
        s4[r] += p;
        Ps[wv][quad * 4 + r][ni * 16 + lr] = (bf16)p;
      }
#pragma unroll
    for (int s = 1; s < 16; s <<= 1)
#pragma unroll
      for (int r = 0; r < 4; r++) s4[r] += __shfl_xor(s4[r], s, 64);
#pragma unroll
    for (int r = 0; r < 4; r++) lrow[r] = lrow[r] * alpha[r] + s4[r];
#pragma unroll
    for (int ni = 0; ni < 4; ni++)
#pragma unroll
      for (int r = 0; r < 4; r++) oacc[ni][r] *= alpha[r];

#pragma unroll
    for (int kb = 0; kb < 4; kb++) {
      bf16x8 ap = *(const bf16x8*)(&Ps[wv][lr][kb * 32 + quad * 8]);
#pragma unroll
      for (int ni = 0; ni < 4; ni++) {
        bf16x8 bv = *(const bf16x8*)(&Vt[ni * 16 + lr][kb * 32 + quad * 8]);
        oacc[ni] = __builtin_amdgcn_mfma_f32_16x16x32_bf16(ap, bv, oacc[ni], 0, 0, 0);
      }
    }
  }

#pragma unroll
  for (int r = 0; r < 4; r++) {
    int bnI = rowbase + q0 + wv * 16 + quad * 4 + r;
    float ms = msim[(size_t)bnI * 12 + h], ls = lsim[(size_t)bnI * 12 + h];
    float mt = fmaxf(mrow[r], ms);
    float ea = __expf(mrow[r] - mt), eb = __expf(ms - mt);
    float inv = 1.f / (lrow[r] * ea + ls * eb);
#pragma unroll
    for (int ni = 0; ni < 4; ni++) {
      int d = ni * 16 + lr;
      float val = (oacc[ni][r] * ea + osim[(size_t)bnI * 768 + h * 64 + d] * eb) * inv;
      attn_out[(size_t)bnI * 768 + h * 64 + d] = (bf16)val;
    }
  }
}

// ---------------------------------------------------------------- launch
extern "C" void kernel_launch(void* const* d_in, const int* in_sizes, int n_in,
                              void* d_out, int out_size, void* d_ws, size_t ws_size,
                              hipStream_t stream) {
  const float* x   = (const float*)d_in[0];
  const float* sim = (const float*)d_in[1];
  const float* Wq  = (const float*)d_in[2];
  const float* bq  = (const float*)d_in[3];
  const float* Wkv = (const float*)d_in[4];
  const float* bkv = (const float*)d_in[5];
  const float* Wp  = (const float*)d_in[6];
  const float* bp  = (const float*)d_in[7];
  float* out = (float*)d_out;

  char* ws = (char*)d_ws;
  size_t off = 0;
  auto carve = [&](size_t bytes) -> char* {
    char* p = ws + off;
    off = (off + bytes + 255) & ~(size_t)255;
    return p;
  };
  bf16*  xb    = (bf16*) carve((size_t)8192 * 768 * 2);
  bf16*  Wqkvt = (bf16*) carve((size_t)2304 * 768 * 2);
  bf16*  Wpt   = (bf16*) carve((size_t)768 * 768 * 2);
  bf16*  Wkvb  = (bf16*) carve((size_t)768 * 1536 * 2);
  float* bias1 = (float*)carve(2304 * 4);
  bf16*  qkv   = (bf16*) carve((size_t)8192 * 2304 * 2);
  float* msim  = (float*)carve((size_t)8192 * 12 * 4);
  float* lsim  = (float*)carve((size_t)8192 * 12 * 4);
  float* osim  = (float*)carve((size_t)8192 * 768 * 4);
  bf16*  attn  = (bf16*) carve((size_t)8192 * 768 * 2);
  size_t rem = (ws_size > off) ? ws_size - off : 0;
  int CH = 8192;                                   // (b,n) pairs per chunk (prefer one-shot)
  while (CH > 128 && (size_t)CH * 18432 > rem) CH >>= 1;
  bf16* U = (bf16*)carve((size_t)CH * 12 * 768 * 2);   // U then S~ in place

  // fused prep: x-cast | Wkv-cast | weight transposes + bias pack
  prep_all<<<16521, 256, 0, stream>>>(x, Wq, Wkv, Wp, bq, bkv, xb, Wqkvt, Wpt, Wkvb, bias1);
  // qkv = x @ [Wq|Wkv] + [bq|bkv]
  gemm_bt<<<dim3(18, 64), 256, 0, stream>>>(xb, Wqkvt, bias1, qkv, nullptr, 8192, 2304, 768);

  int nch = 8192 / CH;
  for (int c = 0; c < nch; c++) {
    int p0 = c * CH;
    // U[bn,h,:] = Q_h[bn,:] @ Wk_h^T   (12 thin GEMMs, K=64)
    gemm_bt_g<<<dim3(12, CH / 128, 12), 256, 0, stream>>>(
        qkv + (size_t)p0 * 2304, 2304, 64,
        Wkvb, 1536, 64,
        U, nullptr, 9216, 768,
        nullptr, 0, nullptr, 0, 64);
    // logits + softmax partials + S~ (in place over U)
    sim_logits<<<CH, 256, 0, stream>>>(sim + (size_t)p0 * 6144, U, qkv, bias1, p0, msim, lsim);
    // osim[bn, h*64+j] = S~_h @ Wv_h + lsim*bv   (12 thin GEMMs, N=64)
    gemm_bt_g<<<dim3(1, CH / 128, 12), 256, 0, stream>>>(
        U, 9216, 768,
        Wqkvt + (size_t)1536 * 768, 768, 64 * 768,
        nullptr, osim + (size_t)p0 * 768, 768, 64,
        bias1 + 1536, 64, lsim + (size_t)p0 * 12, 12, 768);
  }
  self_attn<<<1536, 256, 0, stream>>>(qkv, msim, lsim, osim, attn);
  // out = attn @ Wp + bp (fp32 out)
  gemm_bt<<<dim3(6, 64), 256, 0, stream>>>(attn, Wpt, bp, nullptr, out, 8192, 768, 768);
}